// Round 1
// baseline (3498.009 us; speedup 1.0000x reference)
//
#include <hip/hip_runtime.h>
#include <hip/hip_bf16.h>

// Problem constants (fixed shapes)
constexpr int SEQ    = 2048;   // N tokens
constexpr int HIDDEN = 2048;
constexpr int NHQ    = 16;     // query heads
constexpr int DIM    = 128;    // head dim
constexpr int NCB    = 64;     // compressed blocks  (N-KS)/STRIDE+1
constexpr int NTOP   = 8;      // top-k blocks
constexpr int WINSZ  = 512;

#define SCALEF 0.08838834764831845f
#define NEGF  -1e30f

// ---------------------------------------------------------------------------
// GEMM: C[M,Nd] = A[M,K] @ B[K,Nd], fp32, BM=BN=128, BK=8, 256 thr, 8x8/thr
// requires M%128==0, Nd%128==0, K%8==0
// ---------------------------------------------------------------------------
__global__ __launch_bounds__(256) void gemm128(const float* __restrict__ A,
                                               const float* __restrict__ B,
                                               float* __restrict__ C,
                                               int M, int Nd, int K) {
    __shared__ float As[8][128];
    __shared__ float Bs[8][128];
    const int tid  = threadIdx.x;
    const int brow = blockIdx.y * 128;
    const int bcol = blockIdx.x * 128;
    const int ty = tid >> 4;          // 0..15
    const int tx = tid & 15;          // 0..15
    const int lar = tid >> 1;         // A row 0..127
    const int lac = (tid & 1) * 4;    // A k-offset 0 or 4
    const int lbr = tid >> 5;         // B k-row 0..7
    const int lbc = (tid & 31) * 4;   // B col 0..124

    float acc[8][8];
    #pragma unroll
    for (int i = 0; i < 8; ++i)
        #pragma unroll
        for (int j = 0; j < 8; ++j) acc[i][j] = 0.f;

    for (int k0 = 0; k0 < K; k0 += 8) {
        float4 av = *(const float4*)&A[(size_t)(brow + lar) * K + k0 + lac];
        As[lac + 0][lar] = av.x;
        As[lac + 1][lar] = av.y;
        As[lac + 2][lar] = av.z;
        As[lac + 3][lar] = av.w;
        float4 bv = *(const float4*)&B[(size_t)(k0 + lbr) * Nd + bcol + lbc];
        *(float4*)&Bs[lbr][lbc] = bv;
        __syncthreads();
        #pragma unroll
        for (int kk = 0; kk < 8; ++kk) {
            float a[8], b[8];
            #pragma unroll
            for (int x = 0; x < 8; ++x) a[x] = As[kk][ty * 8 + x];
            #pragma unroll
            for (int x = 0; x < 8; ++x) b[x] = Bs[kk][tx * 8 + x];
            #pragma unroll
            for (int i = 0; i < 8; ++i)
                #pragma unroll
                for (int j = 0; j < 8; ++j)
                    acc[i][j] = fmaf(a[i], b[j], acc[i][j]);
        }
        __syncthreads();
    }
    #pragma unroll
    for (int i = 0; i < 8; ++i)
        #pragma unroll
        for (int j = 0; j < 8; j += 4) {
            *(float4*)&C[(size_t)(brow + ty * 8 + i) * Nd + bcol + tx * 8 + j] =
                make_float4(acc[i][j], acc[i][j+1], acc[i][j+2], acc[i][j+3]);
        }
}

// ---------------------------------------------------------------------------
// Narrow GEMM: BM=32, BN=64, BK=32, 256 thr, 2x4/thr. col-guarded (Nd any).
// requires M%32==0, K%32==0
// ---------------------------------------------------------------------------
__global__ __launch_bounds__(256) void gemm_small(const float* __restrict__ A,
                                                  const float* __restrict__ B,
                                                  float* __restrict__ C,
                                                  int M, int Nd, int K) {
    __shared__ float As[32][33];
    __shared__ float Bs[32][64];
    const int tid  = threadIdx.x;
    const int brow = blockIdx.y * 32;
    const int bcol = blockIdx.x * 64;
    const int ty = tid >> 4;   // 0..15 -> rows ty*2..+1
    const int tx = tid & 15;   // cols tx*4..+3
    float acc[2][4] = {{0.f,0.f,0.f,0.f},{0.f,0.f,0.f,0.f}};

    for (int k0 = 0; k0 < K; k0 += 32) {
        for (int t = tid; t < 1024; t += 256) {
            int r = t >> 5, c = t & 31;            // r = m, c = k
            As[c][r] = A[(size_t)(brow + r) * K + k0 + c];
        }
        for (int t = tid; t < 2048; t += 256) {
            int r = t >> 6, c = t & 63;            // r = k, c = n
            int col = bcol + c;
            Bs[r][c] = (col < Nd) ? B[(size_t)(k0 + r) * Nd + col] : 0.f;
        }
        __syncthreads();
        #pragma unroll 8
        for (int kk = 0; kk < 32; ++kk) {
            float a0 = As[kk][ty * 2], a1 = As[kk][ty * 2 + 1];
            float b0 = Bs[kk][tx * 4], b1 = Bs[kk][tx * 4 + 1];
            float b2 = Bs[kk][tx * 4 + 2], b3 = Bs[kk][tx * 4 + 3];
            acc[0][0] = fmaf(a0, b0, acc[0][0]);
            acc[0][1] = fmaf(a0, b1, acc[0][1]);
            acc[0][2] = fmaf(a0, b2, acc[0][2]);
            acc[0][3] = fmaf(a0, b3, acc[0][3]);
            acc[1][0] = fmaf(a1, b0, acc[1][0]);
            acc[1][1] = fmaf(a1, b1, acc[1][1]);
            acc[1][2] = fmaf(a1, b2, acc[1][2]);
            acc[1][3] = fmaf(a1, b3, acc[1][3]);
        }
        __syncthreads();
    }
    for (int ii = 0; ii < 2; ++ii)
        for (int j = 0; j < 4; ++j) {
            int col = bcol + tx * 4 + j;
            if (col < Nd)
                C[(size_t)(brow + ty * 2 + ii) * Nd + col] = acc[ii][j];
        }
}

// ---------------------------------------------------------------------------
// Compress: ck[m] = rope(mean_s(k[m*32+s] + pe[s]), pos=m*32), cv[m] = mean v
// grid NCB blocks x 128 threads. Reads UN-roped k.
// ---------------------------------------------------------------------------
__global__ void compress_kernel(const float* __restrict__ k,
                                const float* __restrict__ v,
                                const float* __restrict__ pe,
                                float* __restrict__ ck,
                                float* __restrict__ cv) {
    int m = blockIdx.x, d = threadIdx.x;
    float sk = 0.f, sv = 0.f, sp = 0.f;
    for (int s = 0; s < 32; ++s) {
        sk += k[(size_t)(m * 32 + s) * DIM + d];
        sv += v[(size_t)(m * 32 + s) * DIM + d];
        sp += pe[s * DIM + d];
    }
    float ckv = (sk + sp) * (1.0f / 32.0f);
    cv[m * DIM + d] = sv * (1.0f / 32.0f);

    __shared__ float tmp[DIM];
    tmp[d] = ckv;
    __syncthreads();
    int j = d & 63;
    float inv = powf(10000.0f, -(float)(2 * j) / 128.0f);
    float ang = (float)(m * 32) * inv;
    float c = cosf(ang), s = sinf(ang);
    float x1 = tmp[j], x2 = tmp[j + 64];
    ck[m * DIM + d] = (d < 64) ? (x1 * c - x2 * s) : (x2 * c + x1 * s);
}

// ---------------------------------------------------------------------------
// RoPE q (16 heads) and k (1 head) in place. grid SEQ x 64 threads.
// ---------------------------------------------------------------------------
__global__ void rope_qk(float* __restrict__ q, float* __restrict__ k) {
    int i = blockIdx.x, j = threadIdx.x;   // j in [0,64)
    float inv = powf(10000.0f, -(float)(2 * j) / 128.0f);
    float ang = (float)i * inv;
    float c = cosf(ang), s = sinf(ang);
    for (int h = 0; h < NHQ; ++h) {
        float* p = q + ((size_t)i * NHQ + h) * DIM;
        float x1 = p[j], x2 = p[j + 64];
        p[j]      = x1 * c - x2 * s;
        p[j + 64] = x2 * c + x1 * s;
    }
    float* p = k + (size_t)i * DIM;
    float x1 = p[j], x2 = p[j + 64];
    p[j]      = x1 * c - x2 * s;
    p[j + 64] = x2 * c + x1 * s;
}

// ---------------------------------------------------------------------------
// Compressed attention + block scores. grid SEQ x 256 threads.
// comb[i,h,:] = g0 * sum_m p[h][m] cv[m]; blk[i][m] = sum_h p[h][m]
// ---------------------------------------------------------------------------
__global__ __launch_bounds__(256) void cmp_attn(const float* __restrict__ q,
                                                const float* __restrict__ ck,
                                                const float* __restrict__ cv,
                                                const float* __restrict__ gl,
                                                float* __restrict__ comb,
                                                float* __restrict__ blk) {
    int i = blockIdx.x;
    int tid = threadIdx.x;
    __shared__ float qs[NHQ * DIM];      // 8 KB
    __shared__ float cks[NCB * DIM];     // 32 KB
    __shared__ float sc[NHQ * NCB];      // 4 KB

    for (int t = tid; t < NHQ * DIM; t += 256) qs[t] = q[(size_t)i * HIDDEN + t];
    for (int t = tid; t < NCB * DIM; t += 256) cks[t] = ck[t];
    __syncthreads();

    // scores: 16 heads x 64 blocks = 1024 dots of 128
    for (int p = 0; p < 4; ++p) {
        int idx = p * 256 + tid;
        int h = idx >> 6, m = idx & 63;
        bool valid = (i >= m * 32 + 31);
        float r = NEGF;
        if (valid) {
            float acc = 0.f;
            #pragma unroll 16
            for (int d = 0; d < DIM; ++d)
                acc = fmaf(qs[h * DIM + d], cks[m * DIM + d], acc);
            r = acc * SCALEF;
        }
        sc[h * NCB + m] = r;
    }
    __syncthreads();

    // softmax per head (masked entries -> prob 0)
    if (tid < NHQ) {
        int h = tid;
        float mx = NEGF;
        for (int m = 0; m < NCB; ++m) mx = fmaxf(mx, sc[h * NCB + m]);
        if (mx <= NEGF * 0.5f) {
            for (int m = 0; m < NCB; ++m) sc[h * NCB + m] = 0.f;
        } else {
            float z = 0.f;
            for (int m = 0; m < NCB; ++m) {
                float s0 = sc[h * NCB + m];
                float e = (s0 <= NEGF * 0.5f) ? 0.f : expf(s0 - mx);
                sc[h * NCB + m] = e; z += e;
            }
            float rz = 1.0f / z;
            for (int m = 0; m < NCB; ++m) sc[h * NCB + m] *= rz;
        }
    }
    __syncthreads();

    if (tid < NCB) {
        float s = 0.f;
        for (int h = 0; h < NHQ; ++h) s += sc[h * NCB + tid];
        blk[(size_t)i * NCB + tid] = s;
    }

    // out: thread -> (h, 8 d's)
    int h = tid >> 4, d0 = (tid & 15) * 8;
    float o[8] = {0.f,0.f,0.f,0.f,0.f,0.f,0.f,0.f};
    for (int m = 0; m < NCB; ++m) {
        float p = sc[h * NCB + m];
        if (p != 0.f) {
            #pragma unroll
            for (int x = 0; x < 8; ++x)
                o[x] = fmaf(p, cv[m * DIM + d0 + x], o[x]);
        }
    }
    float g0 = 1.0f / (1.0f + expf(-gl[(size_t)i * 48 + h * 3 + 0]));
    #pragma unroll
    for (int x = 0; x < 8; ++x)
        comb[(size_t)i * HIDDEN + h * DIM + d0 + x] = g0 * o[x];
}

// ---------------------------------------------------------------------------
// Top-k selection, exact jax.lax.top_k tie semantics (value desc, index asc).
// one thread per token.
// ---------------------------------------------------------------------------
__global__ void topk_kernel(const float* __restrict__ blk, int* __restrict__ oidx) {
    int i = blockIdx.x * blockDim.x + threadIdx.x;
    if (i >= SEQ) return;
    int tb = i >> 5;  // i / BS
    unsigned long long used = 0ull;
    for (int t = 0; t < NTOP; ++t) {
        float best = -3e38f; int bi = 0;
        for (int m = 0; m < NCB; ++m) {
            if ((used >> m) & 1ull) continue;
            float s = blk[(size_t)i * NCB + m];
            if (m > tb) s = NEGF;                          // future
            if (m == 0 || (m <= tb && m > tb - 2)) s = 1e30f;  // forced
            if (s > best) { best = s; bi = m; }
        }
        used |= 1ull << bi;
        oidx[i * NTOP + t] = bi;
    }
}

// ---------------------------------------------------------------------------
// Sparse (top-k gathered) attention. grid SEQ x 256 threads.
// ---------------------------------------------------------------------------
__global__ __launch_bounds__(256) void sparse_attn(const float* __restrict__ q,
                                                   const float* __restrict__ k,
                                                   const float* __restrict__ v,
                                                   const int* __restrict__ idx,
                                                   const float* __restrict__ gl,
                                                   float* __restrict__ comb) {
    int i = blockIdx.x;
    int tid = threadIdx.x;
    __shared__ float qs[NHQ * DIM];       // 8 KB
    __shared__ float chunk[32 * DIM];     // 16 KB
    __shared__ float ss[NHQ * 256];       // 16 KB
    __shared__ int bidx[NTOP];
    if (tid < NTOP) bidx[tid] = idx[i * NTOP + tid];
    for (int t = tid; t < NHQ * DIM; t += 256) qs[t] = q[(size_t)i * HIDDEN + t];
    __syncthreads();

    // QK over 8 chunks (each = one selected 32-token block)
    for (int c = 0; c < NTOP; ++c) {
        int b = bidx[c];
        for (int t = tid; t < 1024; t += 256) {
            int jl = t >> 5, d4 = (t & 31) * 4;
            *(float4*)&chunk[jl * DIM + d4] =
                *(const float4*)&k[(size_t)(b * 32 + jl) * DIM + d4];
        }
        __syncthreads();
        for (int p = 0; p < 2; ++p) {
            int id2 = p * 256 + tid;
            int h = id2 >> 5, jl = id2 & 31;
            float acc = 0.f;
            #pragma unroll 16
            for (int d = 0; d < DIM; ++d)
                acc = fmaf(qs[h * DIM + d], chunk[jl * DIM + d], acc);
            int pos = b * 32 + jl;
            ss[h * 256 + c * 32 + jl] = (pos <= i) ? acc * SCALEF : NEGF;
        }
        __syncthreads();
    }

    // softmax over 256 per head; wave w handles heads 4w..4w+3
    int wave = tid >> 6, lane = tid & 63;
    for (int hh = 0; hh < 4; ++hh) {
        int h = wave * 4 + hh;
        float mx = NEGF;
        for (int j = lane; j < 256; j += 64) mx = fmaxf(mx, ss[h * 256 + j]);
        for (int o = 32; o; o >>= 1) mx = fmaxf(mx, __shfl_xor(mx, o));
        float z = 0.f;
        for (int j = lane; j < 256; j += 64) {
            float s0 = ss[h * 256 + j];
            float e = (s0 <= NEGF * 0.5f) ? 0.f : expf(s0 - mx);
            ss[h * 256 + j] = e; z += e;
        }
        for (int o = 32; o; o >>= 1) z += __shfl_xor(z, o);
        float rz = 1.0f / z;
        for (int j = lane; j < 256; j += 64) ss[h * 256 + j] *= rz;
    }
    __syncthreads();

    // PV
    int h = tid >> 4, d0 = (tid & 15) * 8;
    float o[8] = {0.f,0.f,0.f,0.f,0.f,0.f,0.f,0.f};
    for (int c = 0; c < NTOP; ++c) {
        int b = bidx[c];
        for (int t = tid; t < 1024; t += 256) {
            int jl = t >> 5, d4 = (t & 31) * 4;
            *(float4*)&chunk[jl * DIM + d4] =
                *(const float4*)&v[(size_t)(b * 32 + jl) * DIM + d4];
        }
        __syncthreads();
        for (int jl = 0; jl < 32; ++jl) {
            float p = ss[h * 256 + c * 32 + jl];
            #pragma unroll
            for (int x = 0; x < 8; ++x)
                o[x] = fmaf(p, chunk[jl * DIM + d0 + x], o[x]);
        }
        __syncthreads();
    }
    float g1 = 1.0f / (1.0f + expf(-gl[(size_t)i * 48 + h * 3 + 1]));
    #pragma unroll
    for (int x = 0; x < 8; ++x)
        comb[(size_t)i * HIDDEN + h * DIM + d0 + x] += g1 * o[x];
}

// ---------------------------------------------------------------------------
// Sliding-window attention: token i attends positions [max(0,i-512), i].
// grid SEQ x 256 threads.
// ---------------------------------------------------------------------------
__global__ __launch_bounds__(256) void swin_attn(const float* __restrict__ q,
                                                 const float* __restrict__ k,
                                                 const float* __restrict__ v,
                                                 const float* __restrict__ gl,
                                                 float* __restrict__ comb) {
    int i = blockIdx.x;
    int tid = threadIdx.x;
    int w0 = (i - WINSZ > 0) ? (i - WINSZ) : 0;
    int cnt = i - w0 + 1;                   // <= 513
    int nch = (cnt + 31) >> 5;              // <= 17 chunks of 32
    __shared__ float qs[NHQ * DIM];         // 8 KB
    __shared__ float chunk[32 * DIM];       // 16 KB
    __shared__ float ss[NHQ * 520];         // 33.3 KB

    for (int t = tid; t < NHQ * DIM; t += 256) qs[t] = q[(size_t)i * HIDDEN + t];
    __syncthreads();

    for (int c = 0; c < nch; ++c) {
        int base = w0 + c * 32;
        int rows = cnt - c * 32; if (rows > 32) rows = 32;
        for (int t = tid; t < rows * 32; t += 256) {
            int jl = t >> 5, d4 = (t & 31) * 4;
            *(float4*)&chunk[jl * DIM + d4] =
                *(const float4*)&k[(size_t)(base + jl) * DIM + d4];
        }
        __syncthreads();
        for (int p = 0; p < 2; ++p) {
            int id2 = p * 256 + tid;
            int h = id2 >> 5, jl = id2 & 31;
            if (jl < rows) {
                float acc = 0.f;
                #pragma unroll 16
                for (int d = 0; d < DIM; ++d)
                    acc = fmaf(qs[h * DIM + d], chunk[jl * DIM + d], acc);
                ss[h * 520 + c * 32 + jl] = acc * SCALEF;
            }
        }
        __syncthreads();
    }

    int wave = tid >> 6, lane = tid & 63;
    for (int hh = 0; hh < 4; ++hh) {
        int h = wave * 4 + hh;
        float mx = -3e38f;
        for (int j = lane; j < cnt; j += 64) mx = fmaxf(mx, ss[h * 520 + j]);
        for (int o = 32; o; o >>= 1) mx = fmaxf(mx, __shfl_xor(mx, o));
        float z = 0.f;
        for (int j = lane; j < cnt; j += 64) {
            float e = expf(ss[h * 520 + j] - mx);
            ss[h * 520 + j] = e; z += e;
        }
        for (int o = 32; o; o >>= 1) z += __shfl_xor(z, o);
        float rz = 1.0f / z;
        for (int j = lane; j < cnt; j += 64) ss[h * 520 + j] *= rz;
    }
    __syncthreads();

    int h = tid >> 4, d0 = (tid & 15) * 8;
    float o[8] = {0.f,0.f,0.f,0.f,0.f,0.f,0.f,0.f};
    for (int c = 0; c < nch; ++c) {
        int base = w0 + c * 32;
        int rows = cnt - c * 32; if (rows > 32) rows = 32;
        for (int t = tid; t < rows * 32; t += 256) {
            int jl = t >> 5, d4 = (t & 31) * 4;
            *(float4*)&chunk[jl * DIM + d4] =
                *(const float4*)&v[(size_t)(base + jl) * DIM + d4];
        }
        __syncthreads();
        for (int jl = 0; jl < rows; ++jl) {
            float p = ss[h * 520 + c * 32 + jl];
            #pragma unroll
            for (int x = 0; x < 8; ++x)
                o[x] = fmaf(p, chunk[jl * DIM + d0 + x], o[x]);
        }
        __syncthreads();
    }
    float g2 = 1.0f / (1.0f + expf(-gl[(size_t)i * 48 + h * 3 + 2]));
    #pragma unroll
    for (int x = 0; x < 8; ++x)
        comb[(size_t)i * HIDDEN + h * DIM + d0 + x] += g2 * o[x];
}

// ---------------------------------------------------------------------------
extern "C" void kernel_launch(void* const* d_in, const int* in_sizes, int n_in,
                              void* d_out, int out_size, void* d_ws, size_t ws_size,
                              hipStream_t stream) {
    const float* x  = (const float*)d_in[0];
    // d_in[1] = cu_seqlens (unused, single sequence)
    const float* Wq = (const float*)d_in[2];
    const float* Wk = (const float*)d_in[3];
    const float* Wv = (const float*)d_in[4];
    const float* Wo = (const float*)d_in[5];
    const float* Wg = (const float*)d_in[6];
    const float* pe = (const float*)d_in[7];
    float* out = (float*)d_out;

    // workspace layout (floats)
    float* q    = (float*)d_ws;                    // 4,194,304
    float* kbuf = q + (size_t)SEQ * HIDDEN;        //   262,144
    float* vbuf = kbuf + (size_t)SEQ * DIM;        //   262,144
    float* gl   = vbuf + (size_t)SEQ * DIM;        //    98,304
    float* ck   = gl + (size_t)SEQ * 48;           //     8,192
    float* cv   = ck + NCB * DIM;                  //     8,192
    float* blk  = cv + NCB * DIM;                  //   131,072
    int*   idx  = (int*)(blk + (size_t)SEQ * NCB); //    16,384 ints
    float* comb = (float*)(idx + SEQ * NTOP);      // 4,194,304

    // 1. projections
    gemm128   <<<dim3(16, 16), 256, 0, stream>>>(x, Wq, q,    SEQ, HIDDEN, HIDDEN);
    gemm_small<<<dim3(2, 64),  256, 0, stream>>>(x, Wk, kbuf, SEQ, DIM,    HIDDEN);
    gemm_small<<<dim3(2, 64),  256, 0, stream>>>(x, Wv, vbuf, SEQ, DIM,    HIDDEN);
    gemm_small<<<dim3(1, 64),  256, 0, stream>>>(x, Wg, gl,   SEQ, 48,     HIDDEN);

    // 2. compress (uses UN-roped k) then rope q,k in place
    compress_kernel<<<NCB, DIM, 0, stream>>>(kbuf, vbuf, pe, ck, cv);
    rope_qk<<<SEQ, 64, 0, stream>>>(q, kbuf);

    // 3. compressed attention (writes comb = g0*out_cmp, blk scores)
    cmp_attn<<<SEQ, 256, 0, stream>>>(q, ck, cv, gl, comb, blk);

    // 4. top-k block selection
    topk_kernel<<<SEQ / 256, 256, 0, stream>>>(blk, idx);

    // 5. sparse attention (comb += g1*out_sp)
    sparse_attn<<<SEQ, 256, 0, stream>>>(q, kbuf, vbuf, idx, gl, comb);

    // 6. sliding-window attention (comb += g2*out_sw)
    swin_attn<<<SEQ, 256, 0, stream>>>(q, kbuf, vbuf, gl, comb);

    // 7. output projection
    gemm128<<<dim3(16, 16), 256, 0, stream>>>(comb, Wo, out, SEQ, HIDDEN, HIDDEN);
}